// Round 4
// baseline (593.242 us; speedup 1.0000x reference)
//
#include <hip/hip_runtime.h>

// O(2) full tensor product, flat-write-order version.
//   input1: (2048, 448), input2: (2048, 160), output: (2048, 71680)
//
// The output row (71680 floats) is exactly 35 pieces of 2048 floats, each
// piece inside a single CG chunk. Grid = row-major over (row, piece) so
// consecutive blocks write consecutive 8 KB regions -> the resident blocks
// form a dense moving window over the 587 MB output (fill-kernel-like HBM
// row locality), instead of 2048 lockstep windows at 280 KB stride.
// Inputs are read directly from global (L2/L3-resident, tiny).
//
// r3 fix: PTYPE[31..32] (chunk 3x1->4 @f4 15872) is sum(5), not diff+(7).

#define R2F  0.70710678118654752440f
#define SQ2F 1.41421356237309504880f

constexpr int BATCH  = 2048;
constexpr int DIM1   = 448;
constexpr int DIM2   = 160;
constexpr int ODIM   = 71680;   // per-row output floats
constexpr int NPIECE = 35;      // 71680 / 2048

typedef float v4f __attribute__((ext_vector_type(4)));

__device__ __forceinline__ void ntst(v4f* p, float x, float y, float z, float w) {
    v4f v = {x, y, z, w};
    __builtin_nontemporal_store(v, p);
}

// piece types: 0=ss, 1=cos, 2=sin, 3=sv, 4=vs, 5=sum, 6=diff(-), 7=diff(+)
// chunk order: ss | cos(1x1) cos(2x2) sin(1x1) sin(2x2) |
//   sv(0x1) vs(1x0) diff-(1x2) diff+(2x1) diff+(3x2) |
//   sv(0x2) sum(1x1) vs(2x0) diff+(3x1) |
//   sum(1x2) sum(2x1) vs(3x0) | sum(2x2) sum(3x1) | sum(3x2)
__constant__ const unsigned char PTYPE[NPIECE] = {
    0, 1, 1, 2, 2,
    3, 3, 4, 4, 6, 6, 7, 7, 7, 7,
    3, 3, 5, 5, 4, 4, 7, 7,
    5, 5, 5, 5, 4, 4,
    5, 5, 5, 5,
    5, 5
};
__constant__ const short AOFF[NPIECE] = {
    0, 64, 192, 64, 192,
    0, 0, 64, 64, 64, 64, 192, 192, 320, 320,
    0, 0, 64, 64, 192, 192, 320, 320,
    64, 64, 192, 192, 320, 320,
    192, 192, 320, 320,
    320, 320
};
__constant__ const short BOFF[NPIECE] = {
    0, 32, 96, 32, 96,
    32, 32, 0, 0, 96, 96, 32, 32, 96, 96,
    96, 96, 32, 32, 0, 0, 32, 32,
    96, 96, 32, 32, 0, 0,
    96, 96, 32, 32,
    96, 96
};
// u-offset of the piece within its (vector) chunk: halves alternate 0,32
__constant__ const short UADD[NPIECE] = {
    0, 0, 0, 0, 0,
    0, 32, 0, 32, 0, 32, 0, 32, 0, 32,
    0, 32, 0, 32, 0, 32, 0, 32,
    0, 32, 0, 32, 0, 32,
    0, 32, 0, 32,
    0, 32
};

__global__ __launch_bounds__(256)
void tp_kernel(const float* __restrict__ g1, const float* __restrict__ g2,
               float* __restrict__ gout) {
    const unsigned g   = blockIdx.x;          // 0 .. 2048*35-1
    const unsigned row = g / NPIECE;          // magic-mul div
    const int      p   = (int)(g - row * NPIECE);
    const int      t0  = threadIdx.x;

    const float* __restrict__ a  = g1 + (size_t)row * DIM1 + AOFF[p];
    const float* __restrict__ bp = g2 + (size_t)row * DIM2 + BOFF[p];
    v4f* out = (v4f*)(gout + (size_t)row * ODIM) + p * 512;

    const int ty = PTYPE[p];

    if (ty <= 2) {
        // scalar-output piece (2048 floats): f4 t in {t0, t0+256}
        // u = t>>3 (u and u+32), v = (4t)&31 (same for both halves)
        const int v = (4 * t0) & 31;
        const int u = t0 >> 3;
        if (ty == 0) {
            // ss: out[u*32+v+i] = a[u]*b[v+i]
            float b0 = bp[v], b1 = bp[v + 1], b2 = bp[v + 2], b3 = bp[v + 3];
            float a0 = a[u], a1 = a[u + 32];
            ntst(out + t0,       a0 * b0, a0 * b1, a0 * b2, a0 * b3);
            ntst(out + t0 + 256, a1 * b0, a1 * b1, a1 * b2, a1 * b3);
        } else {
            const int v2 = 2 * v;
            float e0 = bp[v2],     e1 = bp[v2 + 1], e2 = bp[v2 + 2], e3 = bp[v2 + 3],
                  e4 = bp[v2 + 4], e5 = bp[v2 + 5], e6 = bp[v2 + 6], e7 = bp[v2 + 7];
            float c0 = R2F * a[2 * u],        s0 = R2F * a[2 * u + 1];
            float c1 = R2F * a[2 * u + 64],   s1 = R2F * a[2 * u + 65];  // u+32
            if (ty == 1) {  // cos(a-b): c*bc + s*bs
                ntst(out + t0,       c0*e0 + s0*e1, c0*e2 + s0*e3,
                                     c0*e4 + s0*e5, c0*e6 + s0*e7);
                ntst(out + t0 + 256, c1*e0 + s1*e1, c1*e2 + s1*e3,
                                     c1*e4 + s1*e5, c1*e6 + s1*e7);
            } else {        // sin(a-b): s*bc - c*bs
                ntst(out + t0,       s0*e0 - c0*e1, s0*e2 - c0*e3,
                                     s0*e4 - c0*e5, s0*e6 - c0*e7);
                ntst(out + t0 + 256, s1*e0 - c1*e1, s1*e2 - c1*e3,
                                     s1*e4 - c1*e5, s1*e6 - c1*e7);
            }
        }
    } else {
        // vector-output half-chunk piece: u = UADD + (t0>>4) (+16 for 2nd store),
        // v = (2t0)&31 (invariant across halves)
        const int vI = (2 * t0) & 31;
        const int v2 = 2 * vI;
        const int u0 = UADD[p] + (t0 >> 4);
        const int u1 = u0 + 16;
        if (ty == 3) {
            // sv: sqrt2 * a[u] * b[2v+i]
            float b0 = SQ2F * bp[v2],     b1 = SQ2F * bp[v2 + 1],
                  b2 = SQ2F * bp[v2 + 2], b3 = SQ2F * bp[v2 + 3];
            float a0 = a[u0], a1 = a[u1];
            ntst(out + t0,       a0 * b0, a0 * b1, a0 * b2, a0 * b3);
            ntst(out + t0 + 256, a1 * b0, a1 * b1, a1 * b2, a1 * b3);
        } else if (ty == 4) {
            // vs: sqrt2 * (c*bv, s*bv, c*bv1, s*bv1)
            float bv0 = bp[vI], bv1 = bp[vI + 1];
            float c0 = SQ2F * a[2 * u0], s0 = SQ2F * a[2 * u0 + 1];
            float c1 = SQ2F * a[2 * u1], s1 = SQ2F * a[2 * u1 + 1];
            ntst(out + t0,       c0 * bv0, s0 * bv0, c0 * bv1, s0 * bv1);
            ntst(out + t0 + 256, c1 * bv0, s1 * bv0, c1 * bv1, s1 * bv1);
        } else {
            float bc0 = bp[v2], bs0 = bp[v2 + 1], bc1 = bp[v2 + 2], bs1 = bp[v2 + 3];
            float c0 = a[2 * u0], s0 = a[2 * u0 + 1];
            float c1 = a[2 * u1], s1 = a[2 * u1 + 1];
            if (ty == 5) {
                // sum (m1+m2): (c*bc - s*bs, s*bc + c*bs)
                ntst(out + t0,
                     c0*bc0 - s0*bs0, s0*bc0 + c0*bs0,
                     c0*bc1 - s0*bs1, s0*bc1 + c0*bs1);
                ntst(out + t0 + 256,
                     c1*bc0 - s1*bs0, s1*bc0 + c1*bs0,
                     c1*bc1 - s1*bs1, s1*bc1 + c1*bs1);
            } else {
                // diff (|m1-m2|): (c*bc + s*bs, sgn*(s*bc - c*bs))
                const float sgn = (ty == 6) ? -1.f : 1.f;
                ntst(out + t0,
                     c0*bc0 + s0*bs0, sgn * (s0*bc0 - c0*bs0),
                     c0*bc1 + s0*bs1, sgn * (s0*bc1 - c0*bs1));
                ntst(out + t0 + 256,
                     c1*bc0 + s1*bs0, sgn * (s1*bc0 - c1*bs0),
                     c1*bc1 + s1*bs1, sgn * (s1*bc1 - c1*bs1));
            }
        }
    }
}

extern "C" void kernel_launch(void* const* d_in, const int* in_sizes, int n_in,
                              void* d_out, int out_size, void* d_ws, size_t ws_size,
                              hipStream_t stream) {
    const float* x1 = (const float*)d_in[0];
    const float* x2 = (const float*)d_in[1];
    float* out = (float*)d_out;
    tp_kernel<<<BATCH * NPIECE, 256, 0, stream>>>(x1, x2, out);
}